// Round 5
// baseline (356.622 us; speedup 1.0000x reference)
//
#include <hip/hip_runtime.h>
#include <hip/hip_bf16.h>
#include <cstdint>

// Problem constants: B=4, D=256, DK=DV=32, NH=8, HS=WS=64, NQ=4096, NK=1024

typedef _Float16 f16;
typedef f16 f16x4 __attribute__((ext_vector_type(4)));
typedef f16 f16x8 __attribute__((ext_vector_type(8)));
typedef float f32x4 __attribute__((ext_vector_type(4)));

// ---------------- qcvt + zero init (csum/ssq) ----------------
__launch_bounds__(256)
__global__ void qcvt_zero_kernel(const float* __restrict__ in, f16* __restrict__ out,
                                 float* __restrict__ csum, float* __restrict__ ssq){
    size_t idx = ((size_t)blockIdx.x*256 + threadIdx.x) * 8;
    float4 a = *(const float4*)&in[idx];
    float4 b = *(const float4*)&in[idx+4];
    f16x8 h = { (f16)a.x,(f16)a.y,(f16)a.z,(f16)a.w,(f16)b.x,(f16)b.y,(f16)b.z,(f16)b.w };
    *(f16x8*)&out[idx] = h;
    if (blockIdx.x == 0){
        #pragma unroll
        for (int i = 0; i < 4; ++i) csum[threadIdx.x + i*256] = 0.f;
        if (threadIdx.x < 32) ssq[threadIdx.x] = 0.f;
    }
}

// ---------------- 4x W (256x256 f32, row=k, col=n) -> WT (row=n, col=k) f16 ----------------
__launch_bounds__(256)
__global__ void wcvtT4_kernel(const float* __restrict__ W0, const float* __restrict__ W1,
                              const float* __restrict__ W2, const float* __restrict__ W3,
                              f16* __restrict__ T0, f16* __restrict__ T1,
                              f16* __restrict__ T2, f16* __restrict__ T3){
    const float* W = (blockIdx.z==0)?W0:(blockIdx.z==1)?W1:(blockIdx.z==2)?W2:W3;
    f16* WT = (blockIdx.z==0)?T0:(blockIdx.z==1)?T1:(blockIdx.z==2)?T2:T3;
    __shared__ float L[32][33];
    int r0 = blockIdx.x*32, c0 = blockIdx.y*32;
    int t = threadIdx.x;
    int rr = t >> 3, cc0 = (t & 7)*4;
    float4 v = *(const float4*)&W[(size_t)(r0+rr)*256 + c0 + cc0];
    L[rr][cc0] = v.x; L[rr][cc0+1] = v.y; L[rr][cc0+2] = v.z; L[rr][cc0+3] = v.w;
    __syncthreads();
    int c = t >> 3, rg = (t & 7)*4;
    f16x4 h = { (f16)L[rg][c], (f16)L[rg+1][c], (f16)L[rg+2][c], (f16)L[rg+3][c] };
    *(f16x4*)&WT[(size_t)(c0+c)*256 + r0 + rg] = h;
}

// conv weight OIHW (256,256,3,3) -> wtT[o][khkw*256+c] f16
__launch_bounds__(256)
__global__ void convwT_kernel(const float* __restrict__ w, f16* __restrict__ wtT){
    int o = blockIdx.x, t = threadIdx.x;
    #pragma unroll
    for (int kk = 0; kk < 9; ++kk)
        wtT[(size_t)o*2304 + kk*256 + t] = (f16)w[(size_t)o*2304 + t*9 + kk];
}

// ---------------- double-buffered MFMA GEMM ----------------
// C[M,256] = A[M,K](f16) @ BT[256,K](f16)^T + bias.  256 thr = 4 waves (2x2).
// OUTMODE: 1 = f16 out, 2 = f16 transposed VT[b][n][k] + csum atomics (vproj)
template<int BM, int BN, int OUTMODE>
__launch_bounds__(256)
__global__ void mfma_gemm2(const f16* __restrict__ A, const f16* __restrict__ BT,
                           const float* __restrict__ bias, void* __restrict__ Cout,
                           f16* __restrict__ VT, float* __restrict__ csum, int K){
    constexpr int MI = BM/32, NI = BN/32;
    constexpr int AL = BM/64, BL = BN/64;
    __shared__ f16 As[2][BM][40];
    __shared__ f16 Bs[2][BN][40];
    int t = threadIdx.x;
    int wid = t >> 6, l = t & 63;
    int wr = wid >> 1, wc = wid & 1;
    int lr = l & 15, lg = l >> 4;
    int m0 = blockIdx.x * BM, n0 = blockIdx.y * BN;
    int r = t >> 2, c8 = (t & 3)*8;

    f16x8 ra[AL], rb[BL];
    auto loadc = [&](int k0){
        #pragma unroll
        for (int i = 0; i < AL; ++i)
            ra[i] = *(const f16x8*)&A[(size_t)(m0 + r + i*64)*K + k0 + c8];
        #pragma unroll
        for (int i = 0; i < BL; ++i)
            rb[i] = *(const f16x8*)&BT[(size_t)(n0 + r + i*64)*K + k0 + c8];
    };
    auto writec = [&](int b){
        #pragma unroll
        for (int i = 0; i < AL; ++i) *(f16x8*)&As[b][r + i*64][c8] = ra[i];
        #pragma unroll
        for (int i = 0; i < BL; ++i) *(f16x8*)&Bs[b][r + i*64][c8] = rb[i];
    };

    loadc(0); writec(0); loadc(32);
    __syncthreads();

    f32x4 acc[MI][NI] = {};
    const int nsteps = K >> 5;
    for (int s = 0; s < nsteps; ++s){
        int cb = s & 1;
        f16x8 af[MI], bf[NI];
        #pragma unroll
        for (int mi = 0; mi < MI; ++mi)
            af[mi] = *(const f16x8*)&As[cb][wr*(BM/2) + mi*16 + lr][lg*8];
        #pragma unroll
        for (int ni = 0; ni < NI; ++ni)
            bf[ni] = *(const f16x8*)&Bs[cb][wc*(BN/2) + ni*16 + lr][lg*8];
        if (s + 1 < nsteps){
            writec(cb^1);
            if (s + 2 < nsteps) loadc((s+2)*32);
        }
        #pragma unroll
        for (int mi = 0; mi < MI; ++mi)
            #pragma unroll
            for (int ni = 0; ni < NI; ++ni)
                acc[mi][ni] = __builtin_amdgcn_mfma_f32_16x16x32_f16(af[mi], bf[ni], acc[mi][ni], 0, 0, 0);
        if (s + 1 < nsteps) __syncthreads();
    }

    if (OUTMODE == 1){
        #pragma unroll
        for (int mi = 0; mi < MI; ++mi){
            #pragma unroll
            for (int ni = 0; ni < NI; ++ni){
                int n = n0 + wc*(BN/2) + ni*16 + lr;
                float bv = bias[n];
                #pragma unroll
                for (int j = 0; j < 4; ++j){
                    int m = m0 + wr*(BM/2) + mi*16 + lg*4 + j;
                    ((f16*)Cout)[(size_t)m*256 + n] = (f16)(acc[mi][ni][j] + bv);
                }
            }
        }
    } else {
        // vproj: f16 values -> VT[b][n][k], csum[b*256+n] += col-partials (f16-consistent)
        int b = m0 >> 10;
        #pragma unroll
        for (int ni = 0; ni < NI; ++ni){
            int n = n0 + wc*(BN/2) + ni*16 + lr;
            float bv = bias[n];
            float csp = 0.f;
            #pragma unroll
            for (int mi = 0; mi < MI; ++mi){
                f16x4 hv;
                #pragma unroll
                for (int j = 0; j < 4; ++j){
                    f16 h = (f16)(acc[mi][ni][j] + bv);
                    hv[j] = h;
                    csp += (float)h;
                }
                int m = m0 + wr*(BM/2) + mi*16 + lg*4;
                *(f16x4*)&VT[((size_t)(b*256 + n))*1024 + (m & 1023)] = hv;
            }
            csp += __shfl_xor(csp, 16);
            csp += __shfl_xor(csp, 32);
            if (lg == 0) atomicAdd(&csum[b*256 + n], csp);
        }
    }
}

// ---------------- conv as double-buffered MFMA GEMM ----------------
// Xc[b*1024+pos, o] = im2col(qh) @ wtT^T + srb (f32 out). M=4096, N=256, K=2304.
__launch_bounds__(256)
__global__ void conv2_kernel(const f16* __restrict__ qh, const f16* __restrict__ wtT,
                             const float* __restrict__ srb, float* __restrict__ Xc){
    __shared__ f16 As[2][64][40];
    __shared__ f16 Bs[2][64][40];
    int t = threadIdx.x;
    int wid = t >> 6, l = t & 63;
    int wr = wid >> 1, wc = wid & 1;
    int lr = l & 15, lg = l >> 4;
    int m0 = blockIdx.x * 64, n0 = blockIdx.y * 64;
    int r = t >> 2, c8 = (t & 3)*8;
    int m = m0 + r;
    int bbq = m >> 10, pos = m & 1023;
    int oh = pos >> 5, ow = pos & 31;
    const f16* qb = qh + (size_t)bbq*4096*256;

    f16x8 ra, rbv;
    auto loadc = [&](int k0){
        int khkw = k0 >> 8;
        int kh = (khkw < 3) ? 0 : ((khkw < 6) ? 1 : 2);
        int kw = khkw - kh*3;
        int ih = oh*2 - 1 + kh, iw = ow*2 - 1 + kw;
        int kc = (k0 & 255) + c8;
        f16x8 v = {};
        if ((unsigned)ih < 64u && (unsigned)iw < 64u)
            v = *(const f16x8*)&qb[((size_t)(ih*64 + iw))*256 + kc];
        ra = v;
        rbv = *(const f16x8*)&wtT[(size_t)(n0+r)*2304 + k0 + c8];
    };
    auto writec = [&](int b){
        *(f16x8*)&As[b][r][c8] = ra;
        *(f16x8*)&Bs[b][r][c8] = rbv;
    };

    loadc(0); writec(0); loadc(32);
    __syncthreads();

    f32x4 acc[2][2] = {};
    for (int s = 0; s < 72; ++s){
        int cb = s & 1;
        f16x8 af[2], bf[2];
        #pragma unroll
        for (int mi = 0; mi < 2; ++mi)
            af[mi] = *(const f16x8*)&As[cb][wr*32 + mi*16 + lr][lg*8];
        #pragma unroll
        for (int ni = 0; ni < 2; ++ni)
            bf[ni] = *(const f16x8*)&Bs[cb][wc*32 + ni*16 + lr][lg*8];
        if (s < 71){
            writec(cb^1);
            if (s < 70) loadc((s+2)*32);
        }
        #pragma unroll
        for (int mi = 0; mi < 2; ++mi)
            #pragma unroll
            for (int ni = 0; ni < 2; ++ni)
                acc[mi][ni] = __builtin_amdgcn_mfma_f32_16x16x32_f16(af[mi], bf[ni], acc[mi][ni], 0, 0, 0);
        if (s < 71) __syncthreads();
    }
    #pragma unroll
    for (int mi = 0; mi < 2; ++mi){
        #pragma unroll
        for (int ni = 0; ni < 2; ++ni){
            int n = n0 + wc*32 + ni*16 + lr;
            float bv = srb[n];
            #pragma unroll
            for (int j = 0; j < 4; ++j){
                int mm = m0 + wr*32 + mi*16 + lg*4 + j;
                Xc[(size_t)mm*256 + n] = acc[mi][ni][j] + bv;
            }
        }
    }
}

// ---------------- LayerNorm over D=256, f32 in -> f16 out ----------------
__launch_bounds__(256)
__global__ void ln_kernel(const float* __restrict__ X, f16* __restrict__ Xo,
                          const float* __restrict__ g, const float* __restrict__ b){
    __shared__ float red[256];
    int row = blockIdx.x, t = threadIdx.x;
    float v = X[(size_t)row*256 + t];
    red[t] = v; __syncthreads();
    #pragma unroll
    for (int s=128; s>0; s>>=1){
        if (t < s) red[t] += red[t+s];
        __syncthreads();
    }
    float mu = red[0] * (1.f/256.f);
    __syncthreads();
    float dv = v - mu;
    red[t] = dv*dv; __syncthreads();
    #pragma unroll
    for (int s=128; s>0; s>>=1){
        if (t < s) red[t] += red[t+s];
        __syncthreads();
    }
    float var = red[0] * (1.f/256.f);
    Xo[(size_t)row*256 + t] = (f16)(dv * rsqrtf(var + 1e-5f) * g[t] + b[t]);
}

// ---------------- fused MFMA attention, double-buffered ----------------
// Mix folded into Q (with log2e); swapped QK^T; p~=exp2(L)-1 centered PV; IN stats inline.
// LDS: 2 buffers of {KL 32x264, VTL 256x40}; QL aliases KL[1]. One barrier per 32-k chunk.
__launch_bounds__(512, 4)
__global__ void attn3_kernel(const f16* __restrict__ Qph, const f16* __restrict__ Kh,
                             const f16* __restrict__ VTh, const float* __restrict__ tfw,
                             const float* __restrict__ tfb, const float* __restrict__ csum,
                             float* __restrict__ outu, float* __restrict__ ssq){
    __shared__ f16 KL[2][32][264];
    __shared__ f16 VTL[2][256][40];
    f16 (*QL)[264] = KL[1];

    const int t  = threadIdx.x;
    const int bb = blockIdx.x >> 7;
    const int q0 = (blockIdx.x & 127) * 32;
    const int o  = t >> 6;
    const int l  = t & 63;
    const int g  = l >> 4;
    const int r  = l & 15;

    const f16* Khb = Kh  + (size_t)bb*1024*256;
    const f16* Vtb = VTh + (size_t)bb*256*1024;

    f16x8 rk[2], rv[2];
    // load chunk 0 into regs
    #pragma unroll
    for (int it = 0; it < 2; ++it){
        int e = t + it*512;
        int row = e >> 5, c = (e & 31)*8;
        rk[it] = *(const f16x8*)&Khb[(size_t)row*256 + c];
        int d = e >> 2, qt = (e & 3)*8;
        rv[it] = *(const f16x8*)&Vtb[(size_t)d*1024 + qt];
    }
    // stage Q into QL (= KL[1] region)
    #pragma unroll
    for (int it = 0; it < 2; ++it){
        int e = t + it*512;
        int row = e >> 5, c = (e & 31)*8;
        f16x8 qv = *(const f16x8*)&Qph[((size_t)(bb*4096 + q0 + row))*256 + c];
        *(f16x8*)&QL[row][c] = qv;
    }
    // write chunk 0 -> buffer 0; prefetch chunk 1
    #pragma unroll
    for (int it = 0; it < 2; ++it){
        int e = t + it*512;
        int row = e >> 5, c = (e & 31)*8;
        *(f16x8*)&KL[0][row][c] = rk[it];
        int d = e >> 2, qt = (e & 3)*8;
        *(f16x8*)&VTL[0][d][qt] = rv[it];
    }
    #pragma unroll
    for (int it = 0; it < 2; ++it){
        int e = t + it*512;
        int row = e >> 5, c = (e & 31)*8;
        rk[it] = *(const f16x8*)&Khb[(size_t)(32 + row)*256 + c];
        int d = e >> 2, qt = (e & 3)*8;
        rv[it] = *(const f16x8*)&Vtb[(size_t)d*1024 + 32 + qt];
    }
    __syncthreads();

    const float LOG2E = 1.4426950408889634f;
    const float tb2 = tfb[o] * LOG2E;
    f16x8 qf[2][8];
    #pragma unroll
    for (int i = 0; i < 8; ++i){
        f16 sc = (f16)(tfw[o*8 + i] * (0.17677669529663687f * LOG2E));
        f16x8 scv = { sc,sc,sc,sc,sc,sc,sc,sc };
        #pragma unroll
        for (int qs = 0; qs < 2; ++qs){
            f16x8 v = *(const f16x8*)&QL[qs*16 + r][i*32 + g*8];
            qf[qs][i] = v * scv;
        }
    }
    __syncthreads();  // all qf built before iter0 writes buffer 1

    f32x4 oacc[2][2] = { { {0,0,0,0},{0,0,0,0} }, { {0,0,0,0},{0,0,0,0} } };
    float s_part[2]  = {0.f, 0.f};
    float q2_part[2] = {0.f, 0.f};

    for (int kci = 0; kci < 32; ++kci){
        const int cb = kci & 1;
        const f16 (*KLc)[264] = KL[cb];
        const f16 (*VTLc)[40] = VTL[cb];

        #pragma unroll
        for (int ks = 0; ks < 2; ++ks){
            f16x4 va0 = *(const f16x4*)&VTLc[o*32 + r][ks*16 + g*4];
            f16x4 va1 = *(const f16x4*)&VTLc[o*32 + 16 + r][ks*16 + g*4];
            f32x4 a0 = {0,0,0,0}, a1 = {0,0,0,0};
            #pragma unroll
            for (int i = 0; i < 8; ++i){
                f16x8 kk = *(const f16x8*)&KLc[ks*16 + r][i*32 + g*8];
                a0 = __builtin_amdgcn_mfma_f32_16x16x32_f16(kk, qf[0][i], a0, 0, 0, 0);
                a1 = __builtin_amdgcn_mfma_f32_16x16x32_f16(kk, qf[1][i], a1, 0, 0, 0);
            }
            #pragma unroll
            for (int qs = 0; qs < 2; ++qs){
                f32x4 aa = qs ? a1 : a0;
                f16x4 pb;
                float ps = 0.f, ps2 = 0.f;
                #pragma unroll
                for (int j = 0; j < 4; ++j){
                    float p = exp2f(aa[j] + tb2);
                    ps += p; ps2 += p*p;
                    pb[j] = (f16)(p - 1.0f);
                }
                s_part[qs]  += ps;
                q2_part[qs] += ps2;
                oacc[qs][0] = __builtin_amdgcn_mfma_f32_16x16x16f16(va0, pb, oacc[qs][0], 0, 0, 0);
                oacc[qs][1] = __builtin_amdgcn_mfma_f32_16x16x16f16(va1, pb, oacc[qs][1], 0, 0, 0);
            }
            // between the two compute halves: drain prefetch regs into the other
            // buffer and issue loads two chunks ahead (overlaps with ks=1 compute)
            if (ks == 0 && kci < 31){
                #pragma unroll
                for (int it = 0; it < 2; ++it){
                    int e = t + it*512;
                    int row = e >> 5, c = (e & 31)*8;
                    *(f16x8*)&KL[cb^1][row][c] = rk[it];
                    int d = e >> 2, qt = (e & 3)*8;
                    *(f16x8*)&VTL[cb^1][d][qt] = rv[it];
                }
                if (kci < 30){
                    int kc2 = (kci + 2) * 32;
                    #pragma unroll
                    for (int it = 0; it < 2; ++it){
                        int e = t + it*512;
                        int row = e >> 5, c = (e & 31)*8;
                        rk[it] = *(const f16x8*)&Khb[(size_t)(kc2 + row)*256 + c];
                        int d = e >> 2, qt = (e & 3)*8;
                        rv[it] = *(const f16x8*)&Vtb[(size_t)d*1024 + kc2 + qt];
                    }
                }
            }
        }
        if (kci < 31) __syncthreads();
    }

    // epilogue: per-q sums live across lane groups g (lanes r, r+16, r+32, r+48)
    float s2tot = 0.f;
    #pragma unroll
    for (int qs = 0; qs < 2; ++qs){
        float s = s_part[qs];
        s += __shfl_xor(s, 16);
        s += __shfl_xor(s, 32);
        float inv = 1.0f / s;
        float corrf = (1.0f - s * (1.0f/1024.0f)) * inv;
        float q2 = q2_part[qs];
        q2 += __shfl_xor(q2, 16);
        q2 += __shfl_xor(q2, 32);
        s2tot += q2 * inv * inv;
        int q = q0 + qs*16 + r;
        #pragma unroll
        for (int dh = 0; dh < 2; ++dh){
            int d = o*32 + dh*16 + g*4;
            float4 cs = *(const float4*)&csum[bb*256 + d];
            float4 ov;
            ov.x = oacc[qs][dh][0]*inv + cs.x*corrf;
            ov.y = oacc[qs][dh][1]*inv + cs.y*corrf;
            ov.z = oacc[qs][dh][2]*inv + cs.z*corrf;
            ov.w = oacc[qs][dh][3]*inv + cs.w*corrf;
            *(float4*)&outu[((size_t)(bb*4096 + q))*256 + d] = ov;
        }
    }
    s2tot *= 0.25f;
    #pragma unroll
    for (int off = 1; off < 64; off <<= 1)
        s2tot += __shfl_xor(s2tot, off);
    if (l == 0) atomicAdd(&ssq[bb*8 + o], s2tot);
}

// ---------------- rs[b,h] = rsqrt(ssq/(NQ*NK) - mu^2 + eps) ----------------
__global__ void rs_kernel(const float* __restrict__ ssq, float* __restrict__ rs){
    int t = threadIdx.x;
    const float mu = 1.f/1024.f;
    float var = ssq[t] * (1.f/(4096.f*1024.f)) - mu*mu;
    rs[t] = rsqrtf(var + 1e-5f);
}

// ---------------- final double-buffered MFMA: C = (rs*outu)(f32->f16) @ WoT^T + bo ----------------
__launch_bounds__(256)
__global__ void final2_kernel(const float* __restrict__ A, const f16* __restrict__ WoT,
                              const float* __restrict__ rsb, const float* __restrict__ bo,
                              float* __restrict__ C){
    __shared__ f16 As[2][128][40];
    __shared__ f16 Bs[2][128][40];
    int t = threadIdx.x;
    int wid = t >> 6, l = t & 63;
    int wr = wid >> 1, wc = wid & 1;
    int lr = l & 15, lg = l >> 4;
    int m0 = blockIdx.x * 128, n0 = blockIdx.y * 128;
    int bbatch = m0 >> 12;
    int r = t >> 2, c8 = (t & 3)*8;

    float rs8[8];
    #pragma unroll
    for (int i = 0; i < 8; ++i) rs8[i] = rsb[bbatch*8 + i];

    float4 rfa[4];
    f16x8 rbv[2];
    auto loadc = [&](int k0){
        #pragma unroll
        for (int i = 0; i < 2; ++i){
            const float* ap = &A[(size_t)(m0 + r + i*64)*256 + k0 + c8];
            rfa[2*i]   = *(const float4*)ap;
            rfa[2*i+1] = *(const float4*)(ap+4);
            rbv[i] = *(const f16x8*)&WoT[(size_t)(n0 + r + i*64)*256 + k0 + c8];
        }
    };
    auto writec = [&](int b, int k0){
        float rsk = rs8[k0 >> 5];
        #pragma unroll
        for (int i = 0; i < 2; ++i){
            float4 v0 = rfa[2*i], v1 = rfa[2*i+1];
            f16x8 h = { (f16)(v0.x*rsk),(f16)(v0.y*rsk),(f16)(v0.z*rsk),(f16)(v0.w*rsk),
                        (f16)(v1.x*rsk),(f16)(v1.y*rsk),(f16)(v1.z*rsk),(f16)(v1.w*rsk) };
            *(f16x8*)&As[b][r + i*64][c8] = h;
            *(f16x8*)&Bs[b][r + i*64][c8] = rbv[i];
        }
    };

    loadc(0); writec(0, 0); loadc(32);
    __syncthreads();

    f32x4 acc[4][4] = {};
    for (int s = 0; s < 8; ++s){
        int cb = s & 1;
        f16x8 af[4], bf[4];
        #pragma unroll
        for (int mi = 0; mi < 4; ++mi)
            af[mi] = *(const f16x8*)&As[cb][wr*64 + mi*16 + lr][lg*8];
        #pragma unroll
        for (int ni = 0; ni < 4; ++ni)
            bf[ni] = *(const f16x8*)&Bs[cb][wc*64 + ni*16 + lr][lg*8];
        if (s < 7){
            writec(cb^1, (s+1)*32);
            if (s < 6) loadc((s+2)*32);
        }
        #pragma unroll
        for (int mi = 0; mi < 4; ++mi)
            #pragma unroll
            for (int ni = 0; ni < 4; ++ni)
                acc[mi][ni] = __builtin_amdgcn_mfma_f32_16x16x32_f16(af[mi], bf[ni], acc[mi][ni], 0, 0, 0);
        if (s < 7) __syncthreads();
    }
    #pragma unroll
    for (int mi = 0; mi < 4; ++mi){
        #pragma unroll
        for (int ni = 0; ni < 4; ++ni){
            int n = n0 + wc*64 + ni*16 + lr;
            float bv = bo[n];
            #pragma unroll
            for (int j = 0; j < 4; ++j){
                int m = m0 + wr*64 + mi*16 + lg*4 + j;
                C[(size_t)m*256 + n] = acc[mi][ni][j] + bv;
            }
        }
    }
}

extern "C" void kernel_launch(void* const* d_in, const int* in_sizes, int n_in,
                              void* d_out, int out_size, void* d_ws, size_t ws_size,
                              hipStream_t stream) {
    const float* query = (const float*)d_in[0];
    const float* Wq  = (const float*)d_in[3];
    const float* bq  = (const float*)d_in[4];
    const float* Wk  = (const float*)d_in[5];
    const float* bk  = (const float*)d_in[6];
    const float* Wv  = (const float*)d_in[7];
    const float* bv  = (const float*)d_in[8];
    const float* Wo  = (const float*)d_in[9];
    const float* bo  = (const float*)d_in[10];
    const float* srw = (const float*)d_in[11];
    const float* srb = (const float*)d_in[12];
    const float* lng = (const float*)d_in[13];
    const float* lnb = (const float*)d_in[14];
    const float* tfw = (const float*)d_in[15];
    const float* tfb = (const float*)d_in[16];
    float* out = (float*)d_out;

    float* ws = (float*)d_ws;
    float* outu  = ws;                         // 4,194,304 f32
    f16*   qh    = (f16*)(ws + 4194304);       // 16384x256 f16
    f16*   qbh   = (f16*)(ws + 6291456);       // 16384x256 f16
    float* xconv = ws + 8388608;               // 4096x256 f32
    f16*   xh    = (f16*)(ws + 9437184);       // 4096x256 f16
    f16*   kh    = (f16*)(ws + 9961472);       // 4096x256 f16
    f16*   vth   = (f16*)(ws + 10485760);      // 4x256x1024 f16
    f16*   wtT   = (f16*)(ws + 11010048);      // 256x2304 f16
    f16*   WqT   = (f16*)(ws + 11304960);      // 256x256 f16
    f16*   WkT   = (f16*)(ws + 11337728);
    f16*   WvT   = (f16*)(ws + 11370496);
    f16*   WoT   = (f16*)(ws + 11403264);
    float* csum  = ws + 11436032;              // 1024
    float* ssq   = ws + 11437056;              // 32
    float* rsb   = ws + 11437088;              // 32

    qcvt_zero_kernel<<<2048, 256, 0, stream>>>(query, qh, csum, ssq);
    wcvtT4_kernel<<<dim3(8,8,4), 256, 0, stream>>>(Wq, Wk, Wv, Wo, WqT, WkT, WvT, WoT);
    convwT_kernel<<<256, 256, 0, stream>>>(srw, wtT);

    // q projection -> f16
    mfma_gemm2<128,128,1><<<dim3(128,2), 256, 0, stream>>>(qh, WqT, bq, qbh, nullptr, nullptr, 256);
    // spatial-reduction conv -> f32, then LN -> f16
    conv2_kernel<<<dim3(64,4), 256, 0, stream>>>(qh, wtT, srb, xconv);
    ln_kernel<<<4096, 256, 0, stream>>>(xconv, xh, lng, lnb);
    // k projection -> f16; v projection -> transposed f16 VT + csum
    mfma_gemm2<64,64,1><<<dim3(64,4), 256, 0, stream>>>(xh, WkT, bk, kh, nullptr, nullptr, 256);
    mfma_gemm2<64,64,2><<<dim3(64,4), 256, 0, stream>>>(xh, WvT, bv, nullptr, vth, csum, 256);
    // fused MFMA attention
    attn3_kernel<<<512, 512, 0, stream>>>(qbh, kh, vth, tfw, tfb, csum, outu, ssq);
    rs_kernel<<<1, 32, 0, stream>>>(ssq, rsb);
    // output projection with folded instance-norm scale
    final2_kernel<<<dim3(128,2), 256, 0, stream>>>(outu, WoT, rsb, bo, out);
}

// Round 6
// 342.985 us; speedup vs baseline: 1.0398x; 1.0398x over previous
//
#include <hip/hip_runtime.h>
#include <hip/hip_bf16.h>
#include <cstdint>

// Problem constants: B=4, D=256, DK=DV=32, NH=8, HS=WS=64, NQ=4096, NK=1024

typedef _Float16 f16;
typedef f16 f16x4 __attribute__((ext_vector_type(4)));
typedef f16 f16x8 __attribute__((ext_vector_type(8)));
typedef float f32x4 __attribute__((ext_vector_type(4)));

// async global->LDS, 16B per lane; lds dest must be wave-uniform base (+lane*16 implicit)
__device__ __forceinline__ void gload16(const void* g, void* l){
    __builtin_amdgcn_global_load_lds(
        (const __attribute__((address_space(1))) uint32_t*)g,
        (__attribute__((address_space(3))) uint32_t*)l, 16, 0, 0);
}

// ---------------- qcvt + zero init (csum/ssq) ----------------
__launch_bounds__(256)
__global__ void qcvt_zero_kernel(const float* __restrict__ in, f16* __restrict__ out,
                                 float* __restrict__ csum, float* __restrict__ ssq){
    size_t idx = ((size_t)blockIdx.x*256 + threadIdx.x) * 8;
    float4 a = *(const float4*)&in[idx];
    float4 b = *(const float4*)&in[idx+4];
    f16x8 h = { (f16)a.x,(f16)a.y,(f16)a.z,(f16)a.w,(f16)b.x,(f16)b.y,(f16)b.z,(f16)b.w };
    *(f16x8*)&out[idx] = h;
    if (blockIdx.x == 0){
        #pragma unroll
        for (int i = 0; i < 4; ++i) csum[threadIdx.x + i*256] = 0.f;
        if (threadIdx.x < 32) ssq[threadIdx.x] = 0.f;
    }
}

// ---------------- 4x W (256x256 f32, row=k, col=n) -> WT (row=n, col=k) f16 ----------------
__launch_bounds__(256)
__global__ void wcvtT4_kernel(const float* __restrict__ W0, const float* __restrict__ W1,
                              const float* __restrict__ W2, const float* __restrict__ W3,
                              f16* __restrict__ T0, f16* __restrict__ T1,
                              f16* __restrict__ T2, f16* __restrict__ T3){
    const float* W = (blockIdx.z==0)?W0:(blockIdx.z==1)?W1:(blockIdx.z==2)?W2:W3;
    f16* WT = (blockIdx.z==0)?T0:(blockIdx.z==1)?T1:(blockIdx.z==2)?T2:T3;
    __shared__ float L[32][33];
    int r0 = blockIdx.x*32, c0 = blockIdx.y*32;
    int t = threadIdx.x;
    int rr = t >> 3, cc0 = (t & 7)*4;
    float4 v = *(const float4*)&W[(size_t)(r0+rr)*256 + c0 + cc0];
    L[rr][cc0] = v.x; L[rr][cc0+1] = v.y; L[rr][cc0+2] = v.z; L[rr][cc0+3] = v.w;
    __syncthreads();
    int c = t >> 3, rg = (t & 7)*4;
    f16x4 h = { (f16)L[rg][c], (f16)L[rg+1][c], (f16)L[rg+2][c], (f16)L[rg+3][c] };
    *(f16x4*)&WT[(size_t)(c0+c)*256 + r0 + rg] = h;
}

// conv weight OIHW (256,256,3,3) -> wtT[o][khkw*256+c] f16
__launch_bounds__(256)
__global__ void convwT_kernel(const float* __restrict__ w, f16* __restrict__ wtT){
    int o = blockIdx.x, t = threadIdx.x;
    #pragma unroll
    for (int kk = 0; kk < 9; ++kk)
        wtT[(size_t)o*2304 + kk*256 + t] = (f16)w[(size_t)o*2304 + t*9 + kk];
}

// ---------------- double-buffered MFMA GEMM ----------------
// C[M,256] = A[M,K](f16) @ BT[256,K](f16)^T + bias.  256 thr = 4 waves (2x2).
// OUTMODE: 1 = f16 out, 2 = f16 transposed VT[b][n][k] + csum atomics (vproj)
template<int BM, int BN, int OUTMODE>
__launch_bounds__(256)
__global__ void mfma_gemm2(const f16* __restrict__ A, const f16* __restrict__ BT,
                           const float* __restrict__ bias, void* __restrict__ Cout,
                           f16* __restrict__ VT, float* __restrict__ csum, int K){
    constexpr int MI = BM/32, NI = BN/32;
    constexpr int AL = BM/64, BL = BN/64;
    __shared__ f16 As[2][BM][40];
    __shared__ f16 Bs[2][BN][40];
    int t = threadIdx.x;
    int wid = t >> 6, l = t & 63;
    int wr = wid >> 1, wc = wid & 1;
    int lr = l & 15, lg = l >> 4;
    int m0 = blockIdx.x * BM, n0 = blockIdx.y * BN;
    int r = t >> 2, c8 = (t & 3)*8;

    f16x8 ra[AL], rb[BL];
    auto loadc = [&](int k0){
        #pragma unroll
        for (int i = 0; i < AL; ++i)
            ra[i] = *(const f16x8*)&A[(size_t)(m0 + r + i*64)*K + k0 + c8];
        #pragma unroll
        for (int i = 0; i < BL; ++i)
            rb[i] = *(const f16x8*)&BT[(size_t)(n0 + r + i*64)*K + k0 + c8];
    };
    auto writec = [&](int b){
        #pragma unroll
        for (int i = 0; i < AL; ++i) *(f16x8*)&As[b][r + i*64][c8] = ra[i];
        #pragma unroll
        for (int i = 0; i < BL; ++i) *(f16x8*)&Bs[b][r + i*64][c8] = rb[i];
    };

    loadc(0); writec(0); loadc(32);
    __syncthreads();

    f32x4 acc[MI][NI] = {};
    const int nsteps = K >> 5;
    for (int s = 0; s < nsteps; ++s){
        int cb = s & 1;
        f16x8 af[MI], bf[NI];
        #pragma unroll
        for (int mi = 0; mi < MI; ++mi)
            af[mi] = *(const f16x8*)&As[cb][wr*(BM/2) + mi*16 + lr][lg*8];
        #pragma unroll
        for (int ni = 0; ni < NI; ++ni)
            bf[ni] = *(const f16x8*)&Bs[cb][wc*(BN/2) + ni*16 + lr][lg*8];
        if (s + 1 < nsteps){
            writec(cb^1);
            if (s + 2 < nsteps) loadc((s+2)*32);
        }
        #pragma unroll
        for (int mi = 0; mi < MI; ++mi)
            #pragma unroll
            for (int ni = 0; ni < NI; ++ni)
                acc[mi][ni] = __builtin_amdgcn_mfma_f32_16x16x32_f16(af[mi], bf[ni], acc[mi][ni], 0, 0, 0);
        if (s + 1 < nsteps) __syncthreads();
    }

    if (OUTMODE == 1){
        #pragma unroll
        for (int mi = 0; mi < MI; ++mi){
            #pragma unroll
            for (int ni = 0; ni < NI; ++ni){
                int n = n0 + wc*(BN/2) + ni*16 + lr;
                float bv = bias[n];
                #pragma unroll
                for (int j = 0; j < 4; ++j){
                    int m = m0 + wr*(BM/2) + mi*16 + lg*4 + j;
                    ((f16*)Cout)[(size_t)m*256 + n] = (f16)(acc[mi][ni][j] + bv);
                }
            }
        }
    } else {
        // vproj: f16 values -> VT[b][n][k], csum[b*256+n] += col-partials (f16-consistent)
        int b = m0 >> 10;
        #pragma unroll
        for (int ni = 0; ni < NI; ++ni){
            int n = n0 + wc*(BN/2) + ni*16 + lr;
            float bv = bias[n];
            float csp = 0.f;
            #pragma unroll
            for (int mi = 0; mi < MI; ++mi){
                f16x4 hv;
                #pragma unroll
                for (int j = 0; j < 4; ++j){
                    f16 h = (f16)(acc[mi][ni][j] + bv);
                    hv[j] = h;
                    csp += (float)h;
                }
                int m = m0 + wr*(BM/2) + mi*16 + lg*4;
                *(f16x4*)&VT[((size_t)(b*256 + n))*1024 + (m & 1023)] = hv;
            }
            csp += __shfl_xor(csp, 16);
            csp += __shfl_xor(csp, 32);
            if (lg == 0) atomicAdd(&csum[b*256 + n], csp);
        }
    }
}

// ---------------- conv as double-buffered MFMA GEMM ----------------
// Xc[b*1024+pos, o] = im2col(qh) @ wtT^T + srb (f32 out). M=4096, N=256, K=2304.
__launch_bounds__(256)
__global__ void conv2_kernel(const f16* __restrict__ qh, const f16* __restrict__ wtT,
                             const float* __restrict__ srb, float* __restrict__ Xc){
    __shared__ f16 As[2][64][40];
    __shared__ f16 Bs[2][64][40];
    int t = threadIdx.x;
    int wid = t >> 6, l = t & 63;
    int wr = wid >> 1, wc = wid & 1;
    int lr = l & 15, lg = l >> 4;
    int m0 = blockIdx.x * 64, n0 = blockIdx.y * 64;
    int r = t >> 2, c8 = (t & 3)*8;
    int m = m0 + r;
    int bbq = m >> 10, pos = m & 1023;
    int oh = pos >> 5, ow = pos & 31;
    const f16* qb = qh + (size_t)bbq*4096*256;

    f16x8 ra, rbv;
    auto loadc = [&](int k0){
        int khkw = k0 >> 8;
        int kh = (khkw < 3) ? 0 : ((khkw < 6) ? 1 : 2);
        int kw = khkw - kh*3;
        int ih = oh*2 - 1 + kh, iw = ow*2 - 1 + kw;
        int kc = (k0 & 255) + c8;
        f16x8 v = {};
        if ((unsigned)ih < 64u && (unsigned)iw < 64u)
            v = *(const f16x8*)&qb[((size_t)(ih*64 + iw))*256 + kc];
        ra = v;
        rbv = *(const f16x8*)&wtT[(size_t)(n0+r)*2304 + k0 + c8];
    };
    auto writec = [&](int b){
        *(f16x8*)&As[b][r][c8] = ra;
        *(f16x8*)&Bs[b][r][c8] = rbv;
    };

    loadc(0); writec(0); loadc(32);
    __syncthreads();

    f32x4 acc[2][2] = {};
    for (int s = 0; s < 72; ++s){
        int cb = s & 1;
        f16x8 af[2], bf[2];
        #pragma unroll
        for (int mi = 0; mi < 2; ++mi)
            af[mi] = *(const f16x8*)&As[cb][wr*32 + mi*16 + lr][lg*8];
        #pragma unroll
        for (int ni = 0; ni < 2; ++ni)
            bf[ni] = *(const f16x8*)&Bs[cb][wc*32 + ni*16 + lr][lg*8];
        if (s < 71){
            writec(cb^1);
            if (s < 70) loadc((s+2)*32);
        }
        #pragma unroll
        for (int mi = 0; mi < 2; ++mi)
            #pragma unroll
            for (int ni = 0; ni < 2; ++ni)
                acc[mi][ni] = __builtin_amdgcn_mfma_f32_16x16x32_f16(af[mi], bf[ni], acc[mi][ni], 0, 0, 0);
        if (s < 71) __syncthreads();
    }
    #pragma unroll
    for (int mi = 0; mi < 2; ++mi){
        #pragma unroll
        for (int ni = 0; ni < 2; ++ni){
            int n = n0 + wc*32 + ni*16 + lr;
            float bv = srb[n];
            #pragma unroll
            for (int j = 0; j < 4; ++j){
                int mm = m0 + wr*32 + mi*16 + lg*4 + j;
                Xc[(size_t)mm*256 + n] = acc[mi][ni][j] + bv;
            }
        }
    }
}

// ---------------- LayerNorm over D=256, f32 in -> f16 out ----------------
__launch_bounds__(256)
__global__ void ln_kernel(const float* __restrict__ X, f16* __restrict__ Xo,
                          const float* __restrict__ g, const float* __restrict__ b){
    __shared__ float red[256];
    int row = blockIdx.x, t = threadIdx.x;
    float v = X[(size_t)row*256 + t];
    red[t] = v; __syncthreads();
    #pragma unroll
    for (int s=128; s>0; s>>=1){
        if (t < s) red[t] += red[t+s];
        __syncthreads();
    }
    float mu = red[0] * (1.f/256.f);
    __syncthreads();
    float dv = v - mu;
    red[t] = dv*dv; __syncthreads();
    #pragma unroll
    for (int s=128; s>0; s>>=1){
        if (t < s) red[t] += red[t+s];
        __syncthreads();
    }
    float var = red[0] * (1.f/256.f);
    Xo[(size_t)row*256 + t] = (f16)(dv * rsqrtf(var + 1e-5f) * g[t] + b[t]);
}

// ---------------- fused MFMA attention, global_load_lds double-buffered ----------------
// Mix folded into Q (with log2e); swapped QK^T; p~=exp2(L)-1 centered PV; IN stats inline.
// LDS: KL[2] 32x256 f16 rows 512B, byte ^= (row&7)<<4; VTL[2] 256x32 f16 rows 64B,
// byte ^= ((d&3)^((d>>2)&3))<<4. Staged via global_load_lds with pre-swizzled global src
// (linear LDS dest). One __syncthreads (implicit vmcnt(0) drain) per 32-k chunk.
__launch_bounds__(512, 4)
__global__ void attn4_kernel(const f16* __restrict__ Qph, const f16* __restrict__ Kh,
                             const f16* __restrict__ VTh, const float* __restrict__ tfw,
                             const float* __restrict__ tfb, const float* __restrict__ csum,
                             float* __restrict__ outu, float* __restrict__ ssq){
    __shared__ f16 KL[2][32*256];
    __shared__ f16 VTL[2][256*32];

    const int t  = threadIdx.x;
    const int bb = blockIdx.x >> 7;
    const int q0 = (blockIdx.x & 127) * 32;
    const int o  = t >> 6;          // wave = output head
    const int l  = t & 63;
    const int g  = l >> 4;
    const int r  = l & 15;
    const int wb = o * 2048;        // wave's byte slice of each 16KB tile

    const char* kbase = (const char*)(Kh  + (size_t)bb*1024*256);
    const char* vbase = (const char*)(VTh + (size_t)bb*256*1024);

    // per-lane pre-swizzled global source offsets (chunk 0); two 1KB transfers per wave per tile
    const int o1 = wb + l*16, o2 = o1 + 1024;
    const int kr1 = o1 >> 9,  kr2 = o2 >> 9;
    const char* ks1 = kbase + kr1*512 + ((o1 & 511) ^ ((kr1 & 7) << 4));
    const char* ks2 = kbase + kr2*512 + ((o2 & 511) ^ ((kr2 & 7) << 4));
    const int vd1 = o1 >> 6,  vd2 = o2 >> 6;
    const char* vs1 = vbase + vd1*2048 + ((o1 & 63) ^ ((((vd1&3)^((vd1>>2)&3))) << 4));
    const char* vs2 = vbase + vd2*2048 + ((o2 & 63) ^ ((((vd2&3)^((vd2>>2)&3))) << 4));

    auto stage = [&](int buf, int chunk){
        char* kd = (char*)&KL[buf][0]  + wb;
        char* vd = (char*)&VTL[buf][0] + wb;
        gload16(ks1 + chunk*16384, kd);
        gload16(ks2 + chunk*16384, kd + 1024);
        gload16(vs1 + chunk*64,    vd);
        gload16(vs2 + chunk*64,    vd + 1024);
    };

    stage(0, 0);   // chunk 0 -> buf 0 (in flight)

    // stage Q (32x256 f16) into KL[1] region with the K swizzle (reg path, read-side XOR matches)
    #pragma unroll
    for (int it = 0; it < 2; ++it){
        int e = t + it*512;
        int row = e >> 5;
        int cb = (e & 31) * 16;
        f16x8 qv = *(const f16x8*)&Qph[((size_t)(bb*4096 + q0 + row))*256 + (e & 31)*8];
        *(f16x8*)((char*)&KL[1][0] + row*512 + (cb ^ ((row & 7) << 4))) = qv;
    }
    __syncthreads();   // drains gload (chunk0) + Q ds_writes

    const float LOG2E = 1.4426950408889634f;
    const float tb2 = tfb[o] * LOG2E;
    const int qsw = (r & 7) << 4;
    const char* QLb = (const char*)&KL[1][0];
    f16x8 qf[2][8];
    #pragma unroll
    for (int i = 0; i < 8; ++i){
        f16 sc = (f16)(tfw[o*8 + i] * (0.17677669529663687f * LOG2E));
        f16x8 scv = { sc,sc,sc,sc,sc,sc,sc,sc };
        #pragma unroll
        for (int qs = 0; qs < 2; ++qs){
            f16x8 v = *(const f16x8*)(QLb + (qs*16 + r)*512 + ((i*64 + g*16) ^ qsw));
            qf[qs][i] = v * scv;
        }
    }
    __syncthreads();   // all waves done reading Q before buf1 gets chunk 1

    f32x4 oacc[2][2] = { { {0,0,0,0},{0,0,0,0} }, { {0,0,0,0},{0,0,0,0} } };
    float s_part[2]  = {0.f, 0.f};
    float q2_part[2] = {0.f, 0.f};
    const int vsw = ((r & 3) ^ ((r >> 2) & 3)) << 4;

    for (int kci = 0; kci < 32; ++kci){
        const int cb = kci & 1;
        if (kci < 31) stage(cb^1, kci+1);   // async, lands before next barrier's drain
        const char* KLb = (const char*)&KL[cb][0];
        const char* VLb = (const char*)&VTL[cb][0];

        #pragma unroll
        for (int ks = 0; ks < 2; ++ks){
            f16x4 va0 = *(const f16x4*)(VLb + (o*32 + r)*64      + ((ks*32 + g*8) ^ vsw));
            f16x4 va1 = *(const f16x4*)(VLb + (o*32 + 16 + r)*64 + ((ks*32 + g*8) ^ vsw));
            f32x4 a0 = {0,0,0,0}, a1 = {0,0,0,0};
            #pragma unroll
            for (int i = 0; i < 8; ++i){
                f16x8 kk = *(const f16x8*)(KLb + (ks*16 + r)*512 + ((i*64 + g*16) ^ qsw));
                a0 = __builtin_amdgcn_mfma_f32_16x16x32_f16(kk, qf[0][i], a0, 0, 0, 0);
                a1 = __builtin_amdgcn_mfma_f32_16x16x32_f16(kk, qf[1][i], a1, 0, 0, 0);
            }
            #pragma unroll
            for (int qs = 0; qs < 2; ++qs){
                f32x4 aa = qs ? a1 : a0;
                f16x4 pb;
                float ps = 0.f, ps2 = 0.f;
                #pragma unroll
                for (int j = 0; j < 4; ++j){
                    float p = exp2f(aa[j] + tb2);
                    ps += p; ps2 += p*p;
                    pb[j] = (f16)(p - 1.0f);
                }
                s_part[qs]  += ps;
                q2_part[qs] += ps2;
                oacc[qs][0] = __builtin_amdgcn_mfma_f32_16x16x16f16(va0, pb, oacc[qs][0], 0, 0, 0);
                oacc[qs][1] = __builtin_amdgcn_mfma_f32_16x16x16f16(va1, pb, oacc[qs][1], 0, 0, 0);
            }
        }
        if (kci < 31) __syncthreads();
    }

    // epilogue: per-q sums live across lane groups g (lanes r, r+16, r+32, r+48)
    float s2tot = 0.f;
    #pragma unroll
    for (int qs = 0; qs < 2; ++qs){
        float s = s_part[qs];
        s += __shfl_xor(s, 16);
        s += __shfl_xor(s, 32);
        float inv = 1.0f / s;
        float corrf = (1.0f - s * (1.0f/1024.0f)) * inv;
        float q2 = q2_part[qs];
        q2 += __shfl_xor(q2, 16);
        q2 += __shfl_xor(q2, 32);
        s2tot += q2 * inv * inv;
        int q = q0 + qs*16 + r;
        #pragma unroll
        for (int dh = 0; dh < 2; ++dh){
            int d = o*32 + dh*16 + g*4;
            float4 cs = *(const float4*)&csum[bb*256 + d];
            float4 ov;
            ov.x = oacc[qs][dh][0]*inv + cs.x*corrf;
            ov.y = oacc[qs][dh][1]*inv + cs.y*corrf;
            ov.z = oacc[qs][dh][2]*inv + cs.z*corrf;
            ov.w = oacc[qs][dh][3]*inv + cs.w*corrf;
            *(float4*)&outu[((size_t)(bb*4096 + q))*256 + d] = ov;
        }
    }
    s2tot *= 0.25f;
    #pragma unroll
    for (int off = 1; off < 64; off <<= 1)
        s2tot += __shfl_xor(s2tot, off);
    if (l == 0) atomicAdd(&ssq[bb*8 + o], s2tot);
}

// ---------------- rs[b,h] = rsqrt(ssq/(NQ*NK) - mu^2 + eps) ----------------
__global__ void rs_kernel(const float* __restrict__ ssq, float* __restrict__ rs){
    int t = threadIdx.x;
    const float mu = 1.f/1024.f;
    float var = ssq[t] * (1.f/(4096.f*1024.f)) - mu*mu;
    rs[t] = rsqrtf(var + 1e-5f);
}

// ---------------- final double-buffered MFMA: C = (rs*outu)(f32->f16) @ WoT^T + bo ----------------
__launch_bounds__(256)
__global__ void final2_kernel(const float* __restrict__ A, const f16* __restrict__ WoT,
                              const float* __restrict__ rsb, const float* __restrict__ bo,
                              float* __restrict__ C){
    __shared__ f16 As[2][128][40];
    __shared__ f16 Bs[2][128][40];
    int t = threadIdx.x;
    int wid = t >> 6, l = t & 63;
    int wr = wid >> 1, wc = wid & 1;
    int lr = l & 15, lg = l >> 4;
    int m0 = blockIdx.x * 128, n0 = blockIdx.y * 128;
    int bbatch = m0 >> 12;
    int r = t >> 2, c8 = (t & 3)*8;

    float rs8[8];
    #pragma unroll
    for (int i = 0; i < 8; ++i) rs8[i] = rsb[bbatch*8 + i];

    float4 rfa[4];
    f16x8 rbv[2];
    auto loadc = [&](int k0){
        #pragma unroll
        for (int i = 0; i < 2; ++i){
            const float* ap = &A[(size_t)(m0 + r + i*64)*256 + k0 + c8];
            rfa[2*i]   = *(const float4*)ap;
            rfa[2*i+1] = *(const float4*)(ap+4);
            rbv[i] = *(const f16x8*)&WoT[(size_t)(n0 + r + i*64)*256 + k0 + c8];
        }
    };
    auto writec = [&](int b, int k0){
        float rsk = rs8[k0 >> 5];
        #pragma unroll
        for (int i = 0; i < 2; ++i){
            float4 v0 = rfa[2*i], v1 = rfa[2*i+1];
            f16x8 h = { (f16)(v0.x*rsk),(f16)(v0.y*rsk),(f16)(v0.z*rsk),(f16)(v0.w*rsk),
                        (f16)(v1.x*rsk),(f16)(v1.y*rsk),(f16)(v1.z*rsk),(f16)(v1.w*rsk) };
            *(f16x8*)&As[b][r + i*64][c8] = h;
            *(f16x8*)&Bs[b][r + i*64][c8] = rbv[i];
        }
    };

    loadc(0); writec(0, 0); loadc(32);
    __syncthreads();

    f32x4 acc[4][4] = {};
    for (int s = 0; s < 8; ++s){
        int cb = s & 1;
        f16x8 af[4], bf[4];
        #pragma unroll
        for (int mi = 0; mi < 4; ++mi)
            af[mi] = *(const f16x8*)&As[cb][wr*64 + mi*16 + lr][lg*8];
        #pragma unroll
        for (int ni = 0; ni < 4; ++ni)
            bf[ni] = *(const f16x8*)&Bs[cb][wc*64 + ni*16 + lr][lg*8];
        if (s < 7){
            writec(cb^1, (s+1)*32);
            if (s < 6) loadc((s+2)*32);
        }
        #pragma unroll
        for (int mi = 0; mi < 4; ++mi)
            #pragma unroll
            for (int ni = 0; ni < 4; ++ni)
                acc[mi][ni] = __builtin_amdgcn_mfma_f32_16x16x32_f16(af[mi], bf[ni], acc[mi][ni], 0, 0, 0);
        if (s < 7) __syncthreads();
    }
    #pragma unroll
    for (int mi = 0; mi < 4; ++mi){
        #pragma unroll
        for (int ni = 0; ni < 4; ++ni){
            int n = n0 + wc*64 + ni*16 + lr;
            float bv = bo[n];
            #pragma unroll
            for (int j = 0; j < 4; ++j){
                int m = m0 + wr*64 + mi*16 + lg*4 + j;
                C[(size_t)m*256 + n] = acc[mi][ni][j] + bv;
            }
        }
    }
}

extern "C" void kernel_launch(void* const* d_in, const int* in_sizes, int n_in,
                              void* d_out, int out_size, void* d_ws, size_t ws_size,
                              hipStream_t stream) {
    const float* query = (const float*)d_in[0];
    const float* Wq  = (const float*)d_in[3];
    const float* bq  = (const float*)d_in[4];
    const float* Wk  = (const float*)d_in[5];
    const float* bk  = (const float*)d_in[6];
    const float* Wv  = (const float*)d_in[7];
    const float* bv  = (const float*)d_in[8];
    const float* Wo  = (const float*)d_in[9];
    const float* bo  = (const float*)d_in[10];
    const float* srw = (const float*)d_in[11];
    const float* srb = (const float*)d_in[12];
    const float* lng = (const float*)d_in[13];
    const float* lnb = (const float*)d_in[14];
    const float* tfw = (const float*)d_in[15];
    const float* tfb = (const float*)d_in[16];
    float* out = (float*)d_out;

    float* ws = (float*)d_ws;
    float* outu  = ws;                         // 4,194,304 f32
    f16*   qh    = (f16*)(ws + 4194304);       // 16384x256 f16
    f16*   qbh   = (f16*)(ws + 6291456);       // 16384x256 f16
    float* xconv = ws + 8388608;               // 4096x256 f32
    f16*   xh    = (f16*)(ws + 9437184);       // 4096x256 f16
    f16*   kh    = (f16*)(ws + 9961472);       // 4096x256 f16
    f16*   vth   = (f16*)(ws + 10485760);      // 4x256x1024 f16
    f16*   wtT   = (f16*)(ws + 11010048);      // 256x2304 f16
    f16*   WqT   = (f16*)(ws + 11304960);      // 256x256 f16
    f16*   WkT   = (f16*)(ws + 11337728);
    f16*   WvT   = (f16*)(ws + 11370496);
    f16*   WoT   = (f16*)(ws + 11403264);
    float* csum  = ws + 11436032;              // 1024
    float* ssq   = ws + 11437056;              // 32
    float* rsb   = ws + 11437088;              // 32

    qcvt_zero_kernel<<<2048, 256, 0, stream>>>(query, qh, csum, ssq);
    wcvtT4_kernel<<<dim3(8,8,4), 256, 0, stream>>>(Wq, Wk, Wv, Wo, WqT, WkT, WvT, WoT);
    convwT_kernel<<<256, 256, 0, stream>>>(srw, wtT);

    // q projection -> f16
    mfma_gemm2<128,128,1><<<dim3(128,2), 256, 0, stream>>>(qh, WqT, bq, qbh, nullptr, nullptr, 256);
    // spatial-reduction conv -> f32, then LN -> f16
    conv2_kernel<<<dim3(64,4), 256, 0, stream>>>(qh, wtT, srb, xconv);
    ln_kernel<<<4096, 256, 0, stream>>>(xconv, xh, lng, lnb);
    // k projection -> f16; v projection -> transposed f16 VT + csum
    mfma_gemm2<64,64,1><<<dim3(64,4), 256, 0, stream>>>(xh, WkT, bk, kh, nullptr, nullptr, 256);
    mfma_gemm2<64,64,2><<<dim3(64,4), 256, 0, stream>>>(xh, WvT, bv, nullptr, vth, csum, 256);
    // fused MFMA attention (global_load_lds pipelined)
    attn4_kernel<<<512, 512, 0, stream>>>(qbh, kh, vth, tfw, tfb, csum, outu, ssq);
    rs_kernel<<<1, 32, 0, stream>>>(ssq, rsb);
    // output projection with folded instance-norm scale
    final2_kernel<<<dim3(128,2), 256, 0, stream>>>(outu, WoT, rsb, bo, out);
}

// Round 7
// 336.679 us; speedup vs baseline: 1.0592x; 1.0187x over previous
//
#include <hip/hip_runtime.h>
#include <hip/hip_bf16.h>
#include <cstdint>

// Problem constants: B=4, D=256, DK=DV=32, NH=8, HS=WS=64, NQ=4096, NK=1024

typedef _Float16 f16;
typedef f16 f16x4 __attribute__((ext_vector_type(4)));
typedef f16 f16x8 __attribute__((ext_vector_type(8)));
typedef float f32x4 __attribute__((ext_vector_type(4)));

// async global->LDS, 16B per lane; lds dest must be wave-uniform base (+lane*16 implicit)
__device__ __forceinline__ void gload16(const void* g, void* l){
    __builtin_amdgcn_global_load_lds(
        (const __attribute__((address_space(1))) uint32_t*)g,
        (__attribute__((address_space(3))) uint32_t*)l, 16, 0, 0);
}

// ---------------- qcvt + zero init (csum/ssq) ----------------
__launch_bounds__(256)
__global__ void qcvt_zero_kernel(const float* __restrict__ in, f16* __restrict__ out,
                                 float* __restrict__ csum, float* __restrict__ ssq){
    size_t idx = ((size_t)blockIdx.x*256 + threadIdx.x) * 8;
    float4 a = *(const float4*)&in[idx];
    float4 b = *(const float4*)&in[idx+4];
    f16x8 h = { (f16)a.x,(f16)a.y,(f16)a.z,(f16)a.w,(f16)b.x,(f16)b.y,(f16)b.z,(f16)b.w };
    *(f16x8*)&out[idx] = h;
    if (blockIdx.x == 0){
        #pragma unroll
        for (int i = 0; i < 4; ++i) csum[threadIdx.x + i*256] = 0.f;
        if (threadIdx.x < 32) ssq[threadIdx.x] = 0.f;
    }
}

// ---------------- 4x W (256x256 f32, row=k, col=n) -> WT (row=n, col=k) f16 ----------------
__launch_bounds__(256)
__global__ void wcvtT4_kernel(const float* __restrict__ W0, const float* __restrict__ W1,
                              const float* __restrict__ W2, const float* __restrict__ W3,
                              f16* __restrict__ T0, f16* __restrict__ T1,
                              f16* __restrict__ T2, f16* __restrict__ T3){
    const float* W = (blockIdx.z==0)?W0:(blockIdx.z==1)?W1:(blockIdx.z==2)?W2:W3;
    f16* WT = (blockIdx.z==0)?T0:(blockIdx.z==1)?T1:(blockIdx.z==2)?T2:T3;
    __shared__ float L[32][33];
    int r0 = blockIdx.x*32, c0 = blockIdx.y*32;
    int t = threadIdx.x;
    int rr = t >> 3, cc0 = (t & 7)*4;
    float4 v = *(const float4*)&W[(size_t)(r0+rr)*256 + c0 + cc0];
    L[rr][cc0] = v.x; L[rr][cc0+1] = v.y; L[rr][cc0+2] = v.z; L[rr][cc0+3] = v.w;
    __syncthreads();
    int c = t >> 3, rg = (t & 7)*4;
    f16x4 h = { (f16)L[rg][c], (f16)L[rg+1][c], (f16)L[rg+2][c], (f16)L[rg+3][c] };
    *(f16x4*)&WT[(size_t)(c0+c)*256 + r0 + rg] = h;
}

// conv weight OIHW (256,256,3,3) -> wtT[o][khkw*256+c] f16
__launch_bounds__(256)
__global__ void convwT_kernel(const float* __restrict__ w, f16* __restrict__ wtT){
    int o = blockIdx.x, t = threadIdx.x;
    #pragma unroll
    for (int kk = 0; kk < 9; ++kk)
        wtT[(size_t)o*2304 + kk*256 + t] = (f16)w[(size_t)o*2304 + t*9 + kk];
}

// ---------------- double-buffered MFMA GEMM ----------------
// C[M,256] = A[M,K](f16) @ BT[256,K](f16)^T + bias.  256 thr = 4 waves (2x2).
// OUTMODE: 1 = f16 out, 2 = f16 transposed VT[b][n][k] + csum atomics (vproj)
template<int BM, int BN, int OUTMODE>
__launch_bounds__(256)
__global__ void mfma_gemm2(const f16* __restrict__ A, const f16* __restrict__ BT,
                           const float* __restrict__ bias, void* __restrict__ Cout,
                           f16* __restrict__ VT, float* __restrict__ csum, int K){
    constexpr int MI = BM/32, NI = BN/32;
    constexpr int AL = BM/64, BL = BN/64;
    __shared__ f16 As[2][BM][40];
    __shared__ f16 Bs[2][BN][40];
    int t = threadIdx.x;
    int wid = t >> 6, l = t & 63;
    int wr = wid >> 1, wc = wid & 1;
    int lr = l & 15, lg = l >> 4;
    int m0 = blockIdx.x * BM, n0 = blockIdx.y * BN;
    int r = t >> 2, c8 = (t & 3)*8;

    f16x8 ra[AL], rb[BL];
    auto loadc = [&](int k0){
        #pragma unroll
        for (int i = 0; i < AL; ++i)
            ra[i] = *(const f16x8*)&A[(size_t)(m0 + r + i*64)*K + k0 + c8];
        #pragma unroll
        for (int i = 0; i < BL; ++i)
            rb[i] = *(const f16x8*)&BT[(size_t)(n0 + r + i*64)*K + k0 + c8];
    };
    auto writec = [&](int b){
        #pragma unroll
        for (int i = 0; i < AL; ++i) *(f16x8*)&As[b][r + i*64][c8] = ra[i];
        #pragma unroll
        for (int i = 0; i < BL; ++i) *(f16x8*)&Bs[b][r + i*64][c8] = rb[i];
    };

    loadc(0); writec(0); loadc(32);
    __syncthreads();

    f32x4 acc[MI][NI] = {};
    const int nsteps = K >> 5;
    for (int s = 0; s < nsteps; ++s){
        int cb = s & 1;
        f16x8 af[MI], bf[NI];
        #pragma unroll
        for (int mi = 0; mi < MI; ++mi)
            af[mi] = *(const f16x8*)&As[cb][wr*(BM/2) + mi*16 + lr][lg*8];
        #pragma unroll
        for (int ni = 0; ni < NI; ++ni)
            bf[ni] = *(const f16x8*)&Bs[cb][wc*(BN/2) + ni*16 + lr][lg*8];
        if (s + 1 < nsteps){
            writec(cb^1);
            if (s + 2 < nsteps) loadc((s+2)*32);
        }
        #pragma unroll
        for (int mi = 0; mi < MI; ++mi)
            #pragma unroll
            for (int ni = 0; ni < NI; ++ni)
                acc[mi][ni] = __builtin_amdgcn_mfma_f32_16x16x32_f16(af[mi], bf[ni], acc[mi][ni], 0, 0, 0);
        if (s + 1 < nsteps) __syncthreads();
    }

    if (OUTMODE == 1){
        #pragma unroll
        for (int mi = 0; mi < MI; ++mi){
            #pragma unroll
            for (int ni = 0; ni < NI; ++ni){
                int n = n0 + wc*(BN/2) + ni*16 + lr;
                float bv = bias[n];
                #pragma unroll
                for (int j = 0; j < 4; ++j){
                    int m = m0 + wr*(BM/2) + mi*16 + lg*4 + j;
                    ((f16*)Cout)[(size_t)m*256 + n] = (f16)(acc[mi][ni][j] + bv);
                }
            }
        }
    } else {
        // vproj: f16 values -> VT[b][n][k], csum[b*256+n] += col-partials (f16-consistent)
        int b = m0 >> 10;
        #pragma unroll
        for (int ni = 0; ni < NI; ++ni){
            int n = n0 + wc*(BN/2) + ni*16 + lr;
            float bv = bias[n];
            float csp = 0.f;
            #pragma unroll
            for (int mi = 0; mi < MI; ++mi){
                f16x4 hv;
                #pragma unroll
                for (int j = 0; j < 4; ++j){
                    f16 h = (f16)(acc[mi][ni][j] + bv);
                    hv[j] = h;
                    csp += (float)h;
                }
                int m = m0 + wr*(BM/2) + mi*16 + lg*4;
                *(f16x4*)&VT[((size_t)(b*256 + n))*1024 + (m & 1023)] = hv;
            }
            csp += __shfl_xor(csp, 16);
            csp += __shfl_xor(csp, 32);
            if (lg == 0) atomicAdd(&csum[b*256 + n], csp);
        }
    }
}

// ---------------- conv as double-buffered MFMA GEMM ----------------
// Xc[b*1024+pos, o] = im2col(qh) @ wtT^T + srb (f32 out). M=4096, N=256, K=2304.
__launch_bounds__(256)
__global__ void conv2_kernel(const f16* __restrict__ qh, const f16* __restrict__ wtT,
                             const float* __restrict__ srb, float* __restrict__ Xc){
    __shared__ f16 As[2][64][40];
    __shared__ f16 Bs[2][64][40];
    int t = threadIdx.x;
    int wid = t >> 6, l = t & 63;
    int wr = wid >> 1, wc = wid & 1;
    int lr = l & 15, lg = l >> 4;
    int m0 = blockIdx.x * 64, n0 = blockIdx.y * 64;
    int r = t >> 2, c8 = (t & 3)*8;
    int m = m0 + r;
    int bbq = m >> 10, pos = m & 1023;
    int oh = pos >> 5, ow = pos & 31;
    const f16* qb = qh + (size_t)bbq*4096*256;

    f16x8 ra, rbv;
    auto loadc = [&](int k0){
        int khkw = k0 >> 8;
        int kh = (khkw < 3) ? 0 : ((khkw < 6) ? 1 : 2);
        int kw = khkw - kh*3;
        int ih = oh*2 - 1 + kh, iw = ow*2 - 1 + kw;
        int kc = (k0 & 255) + c8;
        f16x8 v = {};
        if ((unsigned)ih < 64u && (unsigned)iw < 64u)
            v = *(const f16x8*)&qb[((size_t)(ih*64 + iw))*256 + kc];
        ra = v;
        rbv = *(const f16x8*)&wtT[(size_t)(n0+r)*2304 + k0 + c8];
    };
    auto writec = [&](int b){
        *(f16x8*)&As[b][r][c8] = ra;
        *(f16x8*)&Bs[b][r][c8] = rbv;
    };

    loadc(0); writec(0); loadc(32);
    __syncthreads();

    f32x4 acc[2][2] = {};
    for (int s = 0; s < 72; ++s){
        int cb = s & 1;
        f16x8 af[2], bf[2];
        #pragma unroll
        for (int mi = 0; mi < 2; ++mi)
            af[mi] = *(const f16x8*)&As[cb][wr*32 + mi*16 + lr][lg*8];
        #pragma unroll
        for (int ni = 0; ni < 2; ++ni)
            bf[ni] = *(const f16x8*)&Bs[cb][wc*32 + ni*16 + lr][lg*8];
        if (s < 71){
            writec(cb^1);
            if (s < 70) loadc((s+2)*32);
        }
        #pragma unroll
        for (int mi = 0; mi < 2; ++mi)
            #pragma unroll
            for (int ni = 0; ni < 2; ++ni)
                acc[mi][ni] = __builtin_amdgcn_mfma_f32_16x16x32_f16(af[mi], bf[ni], acc[mi][ni], 0, 0, 0);
        if (s < 71) __syncthreads();
    }
    #pragma unroll
    for (int mi = 0; mi < 2; ++mi){
        #pragma unroll
        for (int ni = 0; ni < 2; ++ni){
            int n = n0 + wc*32 + ni*16 + lr;
            float bv = srb[n];
            #pragma unroll
            for (int j = 0; j < 4; ++j){
                int mm = m0 + wr*32 + mi*16 + lg*4 + j;
                Xc[(size_t)mm*256 + n] = acc[mi][ni][j] + bv;
            }
        }
    }
}

// ---------------- LayerNorm over D=256, f32 in -> f16 out ----------------
__launch_bounds__(256)
__global__ void ln_kernel(const float* __restrict__ X, f16* __restrict__ Xo,
                          const float* __restrict__ g, const float* __restrict__ b){
    __shared__ float red[256];
    int row = blockIdx.x, t = threadIdx.x;
    float v = X[(size_t)row*256 + t];
    red[t] = v; __syncthreads();
    #pragma unroll
    for (int s=128; s>0; s>>=1){
        if (t < s) red[t] += red[t+s];
        __syncthreads();
    }
    float mu = red[0] * (1.f/256.f);
    __syncthreads();
    float dv = v - mu;
    red[t] = dv*dv; __syncthreads();
    #pragma unroll
    for (int s=128; s>0; s>>=1){
        if (t < s) red[t] += red[t+s];
        __syncthreads();
    }
    float var = red[0] * (1.f/256.f);
    Xo[(size_t)row*256 + t] = (f16)(dv * rsqrtf(var + 1e-5f) * g[t] + b[t]);
}

// ---------------- fused MFMA attention, global_load_lds double-buffered ----------------
// Mix folded into Q (with log2e); swapped QK^T; p~=exp2(L)-1 centered PV; IN stats inline.
// LDS: KL[2] 32x256 f16 rows 512B, byte ^= (row&7)<<4; VTL[2] 256x32 f16 rows 64B,
// byte ^= ((d&3)^((d>>2)&3))<<4. Staged via global_load_lds with pre-swizzled global src
// (linear LDS dest). One __syncthreads (implicit vmcnt(0) drain) per 32-k chunk.
// launch_bounds(512,2): VGPR cap 256 — the (512,4)=128-total cap forced hot-loop
// scratch spills (round 5/6: +80MB sym. FETCH/WRITE). 1 block/CU; latency hidden
// by the 1-chunk-ahead async prefetch, not TLP.
__launch_bounds__(512, 2)
__global__ void attn4_kernel(const f16* __restrict__ Qph, const f16* __restrict__ Kh,
                             const f16* __restrict__ VTh, const float* __restrict__ tfw,
                             const float* __restrict__ tfb, const float* __restrict__ csum,
                             float* __restrict__ outu, float* __restrict__ ssq){
    __shared__ f16 KL[2][32*256];
    __shared__ f16 VTL[2][256*32];

    const int t  = threadIdx.x;
    const int bb = blockIdx.x >> 7;
    const int q0 = (blockIdx.x & 127) * 32;
    const int o  = t >> 6;          // wave = output head
    const int l  = t & 63;
    const int g  = l >> 4;
    const int r  = l & 15;
    const int wb = o * 2048;        // wave's byte slice of each 16KB tile

    const char* kbase = (const char*)(Kh  + (size_t)bb*1024*256);
    const char* vbase = (const char*)(VTh + (size_t)bb*256*1024);

    // per-lane pre-swizzled global source offsets (chunk 0)
    const int o1 = wb + l*16, o2 = o1 + 1024;
    const int kr1 = o1 >> 9,  kr2 = o2 >> 9;
    const char* ks1 = kbase + kr1*512 + ((o1 & 511) ^ ((kr1 & 7) << 4));
    const char* ks2 = kbase + kr2*512 + ((o2 & 511) ^ ((kr2 & 7) << 4));
    const int vd1 = o1 >> 6;
    const char* vs1 = vbase + vd1*2048 + ((o1 & 63) ^ ((((vd1&3)^((vd1>>2)&3))) << 4));
    // vs2 = vs1 + 16*2048: +16 d-rows leaves both swizzle bits unchanged (mod-4 repeat)

    auto stage = [&](int buf, int chunk){
        char* kd = (char*)&KL[buf][0]  + wb;
        char* vd = (char*)&VTL[buf][0] + wb;
        gload16(ks1 + chunk*16384, kd);
        gload16(ks2 + chunk*16384, kd + 1024);
        gload16(vs1 + chunk*64,         vd);
        gload16(vs1 + 32768 + chunk*64, vd + 1024);
    };

    stage(0, 0);   // chunk 0 -> buf 0 (in flight)

    // stage Q (32x256 f16) into KL[1] region with the K swizzle (reg path, read-side XOR matches)
    #pragma unroll
    for (int it = 0; it < 2; ++it){
        int e = t + it*512;
        int row = e >> 5;
        int cb = (e & 31) * 16;
        f16x8 qv = *(const f16x8*)&Qph[((size_t)(bb*4096 + q0 + row))*256 + (e & 31)*8];
        *(f16x8*)((char*)&KL[1][0] + row*512 + (cb ^ ((row & 7) << 4))) = qv;
    }
    __syncthreads();   // drains gload (chunk0) + Q ds_writes

    const float LOG2E = 1.4426950408889634f;
    const float tb2 = tfb[o] * LOG2E;
    const int qsw = (r & 7) << 4;
    const char* QLb = (const char*)&KL[1][0];
    f16x8 qf[2][8];
    #pragma unroll
    for (int i = 0; i < 8; ++i){
        f16 sc = (f16)(tfw[o*8 + i] * (0.17677669529663687f * LOG2E));
        f16x8 scv = { sc,sc,sc,sc,sc,sc,sc,sc };
        #pragma unroll
        for (int qs = 0; qs < 2; ++qs){
            f16x8 v = *(const f16x8*)(QLb + (qs*16 + r)*512 + ((i*64 + g*16) ^ qsw));
            qf[qs][i] = v * scv;
        }
    }
    __syncthreads();   // all waves done reading Q before buf1 gets chunk 1

    f32x4 oacc[2][2] = { { {0,0,0,0},{0,0,0,0} }, { {0,0,0,0},{0,0,0,0} } };
    float s_part[2]  = {0.f, 0.f};
    float q2_part[2] = {0.f, 0.f};
    const int vsw = ((r & 3) ^ ((r >> 2) & 3)) << 4;

    for (int kci = 0; kci < 32; ++kci){
        const int cb = kci & 1;
        if (kci < 31) stage(cb^1, kci+1);   // async, lands before next barrier's drain
        const char* KLb = (const char*)&KL[cb][0];
        const char* VLb = (const char*)&VTL[cb][0];

        #pragma unroll
        for (int ks = 0; ks < 2; ++ks){
            f16x4 va0 = *(const f16x4*)(VLb + (o*32 + r)*64      + ((ks*32 + g*8) ^ vsw));
            f16x4 va1 = *(const f16x4*)(VLb + (o*32 + 16 + r)*64 + ((ks*32 + g*8) ^ vsw));
            f32x4 a0 = {0,0,0,0}, a1 = {0,0,0,0};
            #pragma unroll
            for (int i = 0; i < 8; ++i){
                f16x8 kk = *(const f16x8*)(KLb + (ks*16 + r)*512 + ((i*64 + g*16) ^ qsw));
                a0 = __builtin_amdgcn_mfma_f32_16x16x32_f16(kk, qf[0][i], a0, 0, 0, 0);
                a1 = __builtin_amdgcn_mfma_f32_16x16x32_f16(kk, qf[1][i], a1, 0, 0, 0);
            }
            #pragma unroll
            for (int qs = 0; qs < 2; ++qs){
                f32x4 aa = qs ? a1 : a0;
                f16x4 pb;
                float ps = 0.f, ps2 = 0.f;
                #pragma unroll
                for (int j = 0; j < 4; ++j){
                    float p = exp2f(aa[j] + tb2);
                    ps += p; ps2 += p*p;
                    pb[j] = (f16)(p - 1.0f);
                }
                s_part[qs]  += ps;
                q2_part[qs] += ps2;
                oacc[qs][0] = __builtin_amdgcn_mfma_f32_16x16x16f16(va0, pb, oacc[qs][0], 0, 0, 0);
                oacc[qs][1] = __builtin_amdgcn_mfma_f32_16x16x16f16(va1, pb, oacc[qs][1], 0, 0, 0);
            }
        }
        if (kci < 31) __syncthreads();
    }

    // epilogue: per-q sums live across lane groups g (lanes r, r+16, r+32, r+48)
    float s2tot = 0.f;
    #pragma unroll
    for (int qs = 0; qs < 2; ++qs){
        float s = s_part[qs];
        s += __shfl_xor(s, 16);
        s += __shfl_xor(s, 32);
        float inv = 1.0f / s;
        float corrf = (1.0f - s * (1.0f/1024.0f)) * inv;
        float q2 = q2_part[qs];
        q2 += __shfl_xor(q2, 16);
        q2 += __shfl_xor(q2, 32);
        s2tot += q2 * inv * inv;
        int q = q0 + qs*16 + r;
        #pragma unroll
        for (int dh = 0; dh < 2; ++dh){
            int d = o*32 + dh*16 + g*4;
            float4 cs = *(const float4*)&csum[bb*256 + d];
            float4 ov;
            ov.x = oacc[qs][dh][0]*inv + cs.x*corrf;
            ov.y = oacc[qs][dh][1]*inv + cs.y*corrf;
            ov.z = oacc[qs][dh][2]*inv + cs.z*corrf;
            ov.w = oacc[qs][dh][3]*inv + cs.w*corrf;
            *(float4*)&outu[((size_t)(bb*4096 + q))*256 + d] = ov;
        }
    }
    s2tot *= 0.25f;
    #pragma unroll
    for (int off = 1; off < 64; off <<= 1)
        s2tot += __shfl_xor(s2tot, off);
    if (l == 0) atomicAdd(&ssq[bb*8 + o], s2tot);
}

// ---------------- rs[b,h] = rsqrt(ssq/(NQ*NK) - mu^2 + eps) ----------------
__global__ void rs_kernel(const float* __restrict__ ssq, float* __restrict__ rs){
    int t = threadIdx.x;
    const float mu = 1.f/1024.f;
    float var = ssq[t] * (1.f/(4096.f*1024.f)) - mu*mu;
    rs[t] = rsqrtf(var + 1e-5f);
}

// ---------------- final double-buffered MFMA: C = (rs*outu)(f32->f16) @ WoT^T + bo ----------------
__launch_bounds__(256)
__global__ void final2_kernel(const float* __restrict__ A, const f16* __restrict__ WoT,
                              const float* __restrict__ rsb, const float* __restrict__ bo,
                              float* __restrict__ C){
    __shared__ f16 As[2][128][40];
    __shared__ f16 Bs[2][128][40];
    int t = threadIdx.x;
    int wid = t >> 6, l = t & 63;
    int wr = wid >> 1, wc = wid & 1;
    int lr = l & 15, lg = l >> 4;
    int m0 = blockIdx.x * 128, n0 = blockIdx.y * 128;
    int bbatch = m0 >> 12;
    int r = t >> 2, c8 = (t & 3)*8;

    float rs8[8];
    #pragma unroll
    for (int i = 0; i < 8; ++i) rs8[i] = rsb[bbatch*8 + i];

    float4 rfa[4];
    f16x8 rbv[2];
    auto loadc = [&](int k0){
        #pragma unroll
        for (int i = 0; i < 2; ++i){
            const float* ap = &A[(size_t)(m0 + r + i*64)*256 + k0 + c8];
            rfa[2*i]   = *(const float4*)ap;
            rfa[2*i+1] = *(const float4*)(ap+4);
            rbv[i] = *(const f16x8*)&WoT[(size_t)(n0 + r + i*64)*256 + k0 + c8];
        }
    };
    auto writec = [&](int b, int k0){
        float rsk = rs8[k0 >> 5];
        #pragma unroll
        for (int i = 0; i < 2; ++i){
            float4 v0 = rfa[2*i], v1 = rfa[2*i+1];
            f16x8 h = { (f16)(v0.x*rsk),(f16)(v0.y*rsk),(f16)(v0.z*rsk),(f16)(v0.w*rsk),
                        (f16)(v1.x*rsk),(f16)(v1.y*rsk),(f16)(v1.z*rsk),(f16)(v1.w*rsk) };
            *(f16x8*)&As[b][r + i*64][c8] = h;
            *(f16x8*)&Bs[b][r + i*64][c8] = rbv[i];
        }
    };

    loadc(0); writec(0, 0); loadc(32);
    __syncthreads();

    f32x4 acc[4][4] = {};
    for (int s = 0; s < 8; ++s){
        int cb = s & 1;
        f16x8 af[4], bf[4];
        #pragma unroll
        for (int mi = 0; mi < 4; ++mi)
            af[mi] = *(const f16x8*)&As[cb][wr*64 + mi*16 + lr][lg*8];
        #pragma unroll
        for (int ni = 0; ni < 4; ++ni)
            bf[ni] = *(const f16x8*)&Bs[cb][wc*64 + ni*16 + lr][lg*8];
        if (s < 7){
            writec(cb^1, (s+1)*32);
            if (s < 6) loadc((s+2)*32);
        }
        #pragma unroll
        for (int mi = 0; mi < 4; ++mi)
            #pragma unroll
            for (int ni = 0; ni < 4; ++ni)
                acc[mi][ni] = __builtin_amdgcn_mfma_f32_16x16x32_f16(af[mi], bf[ni], acc[mi][ni], 0, 0, 0);
        if (s < 7) __syncthreads();
    }
    #pragma unroll
    for (int mi = 0; mi < 4; ++mi){
        #pragma unroll
        for (int ni = 0; ni < 4; ++ni){
            int n = n0 + wc*64 + ni*16 + lr;
            float bv = bo[n];
            #pragma unroll
            for (int j = 0; j < 4; ++j){
                int m = m0 + wr*64 + mi*16 + lg*4 + j;
                C[(size_t)m*256 + n] = acc[mi][ni][j] + bv;
            }
        }
    }
}

extern "C" void kernel_launch(void* const* d_in, const int* in_sizes, int n_in,
                              void* d_out, int out_size, void* d_ws, size_t ws_size,
                              hipStream_t stream) {
    const float* query = (const float*)d_in[0];
    const float* Wq  = (const float*)d_in[3];
    const float* bq  = (const float*)d_in[4];
    const float* Wk  = (const float*)d_in[5];
    const float* bk  = (const float*)d_in[6];
    const float* Wv  = (const float*)d_in[7];
    const float* bv  = (const float*)d_in[8];
    const float* Wo  = (const float*)d_in[9];
    const float* bo  = (const float*)d_in[10];
    const float* srw = (const float*)d_in[11];
    const float* srb = (const float*)d_in[12];
    const float* lng = (const float*)d_in[13];
    const float* lnb = (const float*)d_in[14];
    const float* tfw = (const float*)d_in[15];
    const float* tfb = (const float*)d_in[16];
    float* out = (float*)d_out;

    float* ws = (float*)d_ws;
    float* outu  = ws;                         // 4,194,304 f32
    f16*   qh    = (f16*)(ws + 4194304);       // 16384x256 f16
    f16*   qbh   = (f16*)(ws + 6291456);       // 16384x256 f16
    float* xconv = ws + 8388608;               // 4096x256 f32
    f16*   xh    = (f16*)(ws + 9437184);       // 4096x256 f16
    f16*   kh    = (f16*)(ws + 9961472);       // 4096x256 f16
    f16*   vth   = (f16*)(ws + 10485760);      // 4x256x1024 f16
    f16*   wtT   = (f16*)(ws + 11010048);      // 256x2304 f16
    f16*   WqT   = (f16*)(ws + 11304960);      // 256x256 f16
    f16*   WkT   = (f16*)(ws + 11337728);
    f16*   WvT   = (f16*)(ws + 11370496);
    f16*   WoT   = (f16*)(ws + 11403264);
    float* csum  = ws + 11436032;              // 1024
    float* ssq   = ws + 11437056;              // 32
    float* rsb   = ws + 11437088;              // 32

    qcvt_zero_kernel<<<2048, 256, 0, stream>>>(query, qh, csum, ssq);
    wcvtT4_kernel<<<dim3(8,8,4), 256, 0, stream>>>(Wq, Wk, Wv, Wo, WqT, WkT, WvT, WoT);
    convwT_kernel<<<256, 256, 0, stream>>>(srw, wtT);

    // q projection -> f16
    mfma_gemm2<128,128,1><<<dim3(128,2), 256, 0, stream>>>(qh, WqT, bq, qbh, nullptr, nullptr, 256);
    // spatial-reduction conv -> f32, then LN -> f16
    conv2_kernel<<<dim3(64,4), 256, 0, stream>>>(qh, wtT, srb, xconv);
    ln_kernel<<<4096, 256, 0, stream>>>(xconv, xh, lng, lnb);
    // k projection -> f16; v projection -> transposed f16 VT + csum
    mfma_gemm2<64,64,1><<<dim3(64,4), 256, 0, stream>>>(xh, WkT, bk, kh, nullptr, nullptr, 256);
    mfma_gemm2<64,64,2><<<dim3(64,4), 256, 0, stream>>>(xh, WvT, bv, nullptr, vth, csum, 256);
    // fused MFMA attention (global_load_lds pipelined, spill-free VGPR budget)
    attn4_kernel<<<512, 512, 0, stream>>>(qbh, kh, vth, tfw, tfb, csum, outu, ssq);
    rs_kernel<<<1, 32, 0, stream>>>(ssq, rsb);
    // output projection with folded instance-norm scale
    final2_kernel<<<dim3(128,2), 256, 0, stream>>>(outu, WoT, rsb, bo, out);
}